// Round 2
// baseline (288.668 us; speedup 1.0000x reference)
//
#include <hip/hip_runtime.h>
#include <math.h>

#define BB 32
#define NN 8192
#define DD 128
#define KK 64

// ---------------- Kernel 1: m1c = normalize(normalize(modal1)) ----------------
__global__ __launch_bounds__(128) void norm_m1_kernel(const float* __restrict__ modal1,
                                                      float* __restrict__ m1c) {
    int b = blockIdx.x;
    int d = threadIdx.x;              // 128 threads = 2 waves
    int lane = d & 63, wid = d >> 6;
    float x = modal1[b * DD + d];

    __shared__ float red[2];
    float s = x * x;
    #pragma unroll
    for (int off = 32; off > 0; off >>= 1) s += __shfl_xor(s, off);
    if (lane == 0) red[wid] = s;
    __syncthreads();
    float s1 = red[0] + red[1];
    float inv1 = 1.0f / fmaxf(sqrtf(s1), 1e-12f);
    float m1 = x * inv1;
    __syncthreads();

    float s2p = m1 * m1;
    #pragma unroll
    for (int off = 32; off > 0; off >>= 1) s2p += __shfl_xor(s2p, off);
    if (lane == 0) red[wid] = s2p;
    __syncthreads();
    float s2 = red[0] + red[1];
    float inv2 = 1.0f / fmaxf(sqrtf(s2), 1e-8f);
    m1c[b * DD + d] = m1 * inv2;
}

// ---------------- Kernel 2: cos_sim[b,n], inv_norm[b,n] ----------------
// wave per row; lane holds float2 of the 128-float row (coalesced 512B/wave).
__global__ __launch_bounds__(256) void cos_kernel(const float* __restrict__ modal2,
                                                  const float* __restrict__ m1c,
                                                  float* __restrict__ cos_out,
                                                  float* __restrict__ inv_out) {
    int lane = threadIdx.x & 63;
    int gwave = (blockIdx.x * blockDim.x + threadIdx.x) >> 6;
    int nwaves = (gridDim.x * blockDim.x) >> 6;
    const int total = BB * NN;

    for (int r = gwave; r < total; r += nwaves) {
        int b = r >> 13;  // N = 8192
        const float2 xv = *reinterpret_cast<const float2*>(modal2 + (size_t)r * DD + lane * 2);
        const float2 mv = *reinterpret_cast<const float2*>(m1c + b * DD + lane * 2);
        float ss = xv.x * xv.x + xv.y * xv.y;
        float dd = xv.x * mv.x + xv.y * mv.y;
        #pragma unroll
        for (int off = 32; off > 0; off >>= 1) {
            ss += __shfl_xor(ss, off);
            dd += __shfl_xor(dd, off);
        }
        if (lane == 0) {
            float inv1 = 1.0f / fmaxf(sqrtf(ss), 1e-12f);       // first normalize (eps 1e-12)
            float s2 = ss * inv1 * inv1;                         // ||m2||^2
            float inv2 = 1.0f / fmaxf(sqrtf(s2), 1e-8f);         // cosine_similarity renorm
            cos_out[r] = dd * inv1 * inv2;
            inv_out[r] = inv1;
        }
    }
}

// ---------------- Kernel 3: per-b top-K (ordered) + softmax-weighted gather ----------------
__device__ __forceinline__ unsigned long long packkey(float f, int n) {
    unsigned u = __float_as_uint(f);
    u = (u & 0x80000000u) ? ~u : (u | 0x80000000u);   // monotone-unsigned float
    return ((unsigned long long)u << 32) | (unsigned)(NN - 1 - n);  // ties -> smaller n wins max
}

__global__ __launch_bounds__(256) void topk_kernel(const float* __restrict__ modal2,
                                                   const float* __restrict__ cos_sim,
                                                   const float* __restrict__ inv_norm,
                                                   const float* __restrict__ weights,
                                                   float* __restrict__ out) {
    int b = blockIdx.x;
    int tid = threadIdx.x;
    int lane = tid & 63, wid = tid >> 6;

    __shared__ float vals[NN];                 // 32 KB
    __shared__ int topk_idx[KK];
    __shared__ float coef[KK];
    __shared__ unsigned long long warp_max[4];

    const float* crow = cos_sim + (size_t)b * NN;
    for (int i = tid; i < NN; i += 256) vals[i] = crow[i];
    __syncthreads();

    // per-thread candidate over slots {tid + 256*j} (conflict-free stride)
    unsigned long long best = 0ull;
    #pragma unroll
    for (int j = 0; j < NN / 256; ++j) {
        int n = tid + 256 * j;
        unsigned long long kk2 = packkey(vals[n], n);
        if (kk2 > best) best = kk2;
    }

    for (int k = 0; k < KK; ++k) {
        unsigned long long m = best;
        #pragma unroll
        for (int off = 32; off > 0; off >>= 1) {
            unsigned long long o = __shfl_xor(m, off);
            if (o > m) m = o;
        }
        if (lane == 0) warp_max[wid] = m;
        __syncthreads();
        unsigned long long g = warp_max[0];
        #pragma unroll
        for (int w = 1; w < 4; ++w) if (warp_max[w] > g) g = warp_max[w];
        int widx = NN - 1 - (int)(g & 0xffffffffu);
        if (tid == 0) topk_idx[k] = widx;
        if (best == g) {   // unique winner (index embedded in key)
            vals[widx] = -INFINITY;
            best = 0ull;
            #pragma unroll
            for (int j = 0; j < NN / 256; ++j) {
                int n = tid + 256 * j;
                unsigned long long kk2 = packkey(vals[n], n);
                if (kk2 > best) best = kk2;
            }
        }
        __syncthreads();
    }

    // softmax over weights[b, 0..63] on wave 0; coef[k] = w[k] * inv_norm[b, idx[k]]
    if (wid == 0) {
        float wv = weights[b * KK + lane];
        float mx = wv;
        #pragma unroll
        for (int off = 32; off > 0; off >>= 1) mx = fmaxf(mx, __shfl_xor(mx, off));
        float e = expf(wv - mx);
        float s = e;
        #pragma unroll
        for (int off = 32; off > 0; off >>= 1) s += __shfl_xor(s, off);
        float w = e / s;
        int idx = topk_idx[lane];
        coef[lane] = w * inv_norm[(size_t)b * NN + idx];
    }
    __syncthreads();

    // out[b, d] = sum_k coef[k] * modal2[b, idx[k], d]   (rows are L2/L3-hot)
    if (tid < DD) {
        float acc = 0.f;
        const float* base = modal2 + (size_t)b * NN * DD;
        for (int k = 0; k < KK; ++k) {
            acc += coef[k] * base[(size_t)topk_idx[k] * DD + tid];
        }
        out[b * DD + tid] = acc;
    }
}

extern "C" void kernel_launch(void* const* d_in, const int* in_sizes, int n_in,
                              void* d_out, int out_size, void* d_ws, size_t ws_size,
                              hipStream_t stream) {
    const float* modal1  = (const float*)d_in[0];
    const float* modal2  = (const float*)d_in[1];
    const float* weights = (const float*)d_in[2];
    float* out = (float*)d_out;

    char* ws = (char*)d_ws;
    float* m1c      = (float*)ws;                       // 32*128*4 = 16 KB
    float* cos_sim  = (float*)(ws + 16384);             // 32*8192*4 = 1 MB
    float* inv_norm = (float*)(ws + 16384 + BB * NN * 4);

    norm_m1_kernel<<<BB, 128, 0, stream>>>(modal1, m1c);
    cos_kernel<<<2048, 256, 0, stream>>>(modal2, m1c, cos_sim, inv_norm);
    topk_kernel<<<BB, 256, 0, stream>>>(modal2, cos_sim, inv_norm, weights, out);
}